// Round 11
// baseline (1816.604 us; speedup 1.0000x reference)
//
#include <hip/hip_runtime.h>
#include <math.h>

typedef __attribute__((ext_vector_type(4))) float  f32x4;
typedef __attribute__((ext_vector_type(8))) __bf16 bf16x8;
typedef __attribute__((ext_vector_type(4))) __bf16 bf16x4;

constexpr int B_ = 4, S_ = 2048, E_ = 1024, H_ = 16, D_ = 64;
constexpr int M_ = B_ * S_;   // 8192 rows of x
constexpr int N3 = 3 * E_;    // 3072 qkv cols

__device__ __forceinline__ f32x4 mfma16(bf16x8 a, bf16x8 b, f32x4 c) {
    return __builtin_amdgcn_mfma_f32_16x16x32_bf16(a, b, c, 0, 0, 0);
}
// split fp32 into bf16 hi + bf16 lo (x ≈ hi + lo), RNE both times.
__device__ __forceinline__ void split2(float x, __bf16& h, __bf16& l) {
    h = (__bf16)x;
    l = (__bf16)(x - (float)h);
}

// ===========================================================================
// Fragment-order packs (one-shot, hoists split2 + layout out of GEMM loops).
// Tile (p, kt) occupies 4096 ushorts at ((p*KT + kt)*4096); slot s in [0,512):
//   A-pack: s=(mi*4+lq2)*16+lr2 holds A[p*128+mi*16+lr2][kt*32+lq2*8+j], j=0..7
//   B-pack: s=(ni*4+lq2)*16+lr2 holds B[kt*32+lq2*8+j][p*128+ni*16+lr2]
// These match the HW-verified A/B fragment layouts (rounds 7/9).
// ===========================================================================
__global__ __launch_bounds__(256)
void pack_A_kernel(const float* __restrict__ A, int Kcols,
                   ushort* __restrict__ hi, ushort* __restrict__ lo) {
    const size_t idx = (size_t)blockIdx.x * 256 + threadIdx.x;  // global slot
    const int  slot = (int)(idx & 511);
    const size_t pt = idx >> 9;                 // p*KT + kt
    const int KT = Kcols >> 5;
    const int kt = (int)(pt % KT);
    const int p  = (int)(pt / KT);
    const int lr2 = slot & 15, lq2 = (slot >> 4) & 3, mi = slot >> 6;
    const float* ap = A + (size_t)(p * 128 + mi * 16 + lr2) * Kcols
                        + kt * 32 + lq2 * 8;
    float4 a0 = *reinterpret_cast<const float4*>(ap);
    float4 a1 = *reinterpret_cast<const float4*>(ap + 4);
    float v8[8] = {a0.x, a0.y, a0.z, a0.w, a1.x, a1.y, a1.z, a1.w};
    bf16x8 hv, lv;
#pragma unroll
    for (int j = 0; j < 8; ++j) {
        __bf16 h0, l0;
        split2(v8[j], h0, l0);
        hv[j] = h0; lv[j] = l0;
    }
    *reinterpret_cast<bf16x8*>(hi + idx * 8) = hv;
    *reinterpret_cast<bf16x8*>(lo + idx * 8) = lv;
}

__global__ __launch_bounds__(256)
void pack_B_kernel(const float* __restrict__ Bsrc, int Kdim, int Ncols,
                   ushort* __restrict__ hi, ushort* __restrict__ lo) {
    const size_t idx = (size_t)blockIdx.x * 256 + threadIdx.x;
    const int  slot = (int)(idx & 511);
    const size_t pt = idx >> 9;
    const int KT = Kdim >> 5;
    const int kt = (int)(pt % KT);
    const int p  = (int)(pt / KT);
    const int lr2 = slot & 15, lq2 = (slot >> 4) & 3, ni = slot >> 6;
    const float* bp = Bsrc + (size_t)(kt * 32 + lq2 * 8) * Ncols
                           + p * 128 + ni * 16 + lr2;
    bf16x8 hv, lv;
#pragma unroll
    for (int j = 0; j < 8; ++j) {
        __bf16 h0, l0;
        split2(bp[(size_t)j * Ncols], h0, l0);
        hv[j] = h0; lv[j] = l0;
    }
    *reinterpret_cast<bf16x8*>(hi + idx * 8) = hv;
    *reinterpret_cast<bf16x8*>(lo + idx * 8) = lv;
}

// ===========================================================================
// Packed GEMM core: stage = 8x coalesced 16B loads + 8x linear b128 LDS
// writes per thread per K-step (no VALU split, no strided scalars).
// Compute section identical to round 9 (HW-verified).
// ===========================================================================
__device__ __forceinline__ void gemm_packed_core(
    const ushort* __restrict__ Ah, const ushort* __restrict__ Al,  // panel base
    const ushort* __restrict__ Bh, const ushort* __restrict__ Bl,  // panel base
    int KT,
    __bf16* lAh, __bf16* lAl, __bf16* lBh, __bf16* lBl,
    f32x4 acc[4][4])
{
    const int tid  = threadIdx.x;
    const int lane = tid & 63;
    const int w    = tid >> 6;
    const int lr   = lane & 15;
    const int lq   = lane >> 4;
    const int wm   = w >> 1, wn = w & 1;

    for (int kt = 0; kt < KT; ++kt) {
        __syncthreads();   // protect prior step's LDS reads
        const size_t toff = (size_t)kt * 4096;
#pragma unroll
        for (int i = 0; i < 2; ++i) {
            const int s = tid + 256 * i;
            *reinterpret_cast<bf16x8*>(lAh + s * 8) =
                *reinterpret_cast<const bf16x8*>(Ah + toff + s * 8);
            *reinterpret_cast<bf16x8*>(lAl + s * 8) =
                *reinterpret_cast<const bf16x8*>(Al + toff + s * 8);
            *reinterpret_cast<bf16x8*>(lBh + s * 8) =
                *reinterpret_cast<const bf16x8*>(Bh + toff + s * 8);
            *reinterpret_cast<bf16x8*>(lBl + s * 8) =
                *reinterpret_cast<const bf16x8*>(Bl + toff + s * 8);
        }
        __syncthreads();

        // ---- compute: 16 fragments x 3 split-MFMAs ----
        bf16x8 ah[4], al[4], bh[4], bl[4];
#pragma unroll
        for (int t = 0; t < 4; ++t) {
            const int sa = ((wm * 4 + t) * 4 + lq) * 16 + lr;
            ah[t] = *reinterpret_cast<const bf16x8*>(lAh + sa * 8);
            al[t] = *reinterpret_cast<const bf16x8*>(lAl + sa * 8);
            const int sb = ((wn * 4 + t) * 4 + lq) * 16 + lr;
            bh[t] = *reinterpret_cast<const bf16x8*>(lBh + sb * 8);
            bl[t] = *reinterpret_cast<const bf16x8*>(lBl + sb * 8);
        }
#pragma unroll
        for (int mi = 0; mi < 4; ++mi)
#pragma unroll
            for (int ni = 0; ni < 4; ++ni) {
                acc[mi][ni] = mfma16(ah[mi], bh[ni], acc[mi][ni]);
                acc[mi][ni] = mfma16(al[mi], bh[ni], acc[mi][ni]);
                acc[mi][ni] = mfma16(ah[mi], bl[ni], acc[mi][ni]);
            }
    }
}

// ---------------------------------------------------------------------------
// Kernel 1: qkv GEMM from packs, scatter to Q/K/V [B,H,S,D].
// Grid (N3/128, M/128). Epilogue HW-verified round 9.
// ---------------------------------------------------------------------------
__global__ __launch_bounds__(256, 2)
void qkv_kernel(const ushort* __restrict__ xh, const ushort* __restrict__ xl,
                const ushort* __restrict__ wh, const ushort* __restrict__ wl,
                const float* __restrict__ bias,
                float* __restrict__ Qb, float* __restrict__ Kb,
                float* __restrict__ Vb) {
    __shared__ __align__(16) __bf16 lAh[4096], lAl[4096];
    __shared__ __align__(16) __bf16 lBh[4096], lBl[4096];
    constexpr int KT = E_ / 32;   // 32

    const int pn = blockIdx.x;    // 128-col panel
    const int pm = blockIdx.y;    // 128-row panel
    const int bn = pn * 128, bm = pm * 128;
    const int tid  = threadIdx.x;
    const int lane = tid & 63;
    const int w    = tid >> 6;
    const int lr   = lane & 15;
    const int lq   = lane >> 4;
    const int wm   = w >> 1, wn = w & 1;

    f32x4 acc[4][4];
#pragma unroll
    for (int mi = 0; mi < 4; ++mi)
#pragma unroll
        for (int ni = 0; ni < 4; ++ni) acc[mi][ni] = (f32x4){0.f, 0.f, 0.f, 0.f};

    gemm_packed_core(xh + (size_t)pm * KT * 4096, xl + (size_t)pm * KT * 4096,
                     wh + (size_t)pn * KT * 4096, wl + (size_t)pn * KT * 4096,
                     KT, lAh, lAl, lBh, lBl, acc);

#pragma unroll
    for (int ni = 0; ni < 4; ++ni) {
        const int col  = bn + (wn * 4 + ni) * 16 + lr;
        const int t    = col >> 10;            // q/k/v
        const int hcol = col & 1023;
        const int h    = hcol >> 6;
        const int d    = hcol & 63;
        float* dst = (t == 0) ? Qb : (t == 1) ? Kb : Vb;
        const float bv = bias[col];
#pragma unroll
        for (int mi = 0; mi < 4; ++mi) {
#pragma unroll
            for (int r = 0; r < 4; ++r) {
                const int row = bm + (wm * 4 + mi) * 16 + lq * 4 + r;
                const int b = row >> 11;
                const int s = row & 2047;
                dst[(((size_t)(b * H_ + h)) * S_ + s) * D_ + d] =
                    acc[mi][ni][r] + bv;
            }
        }
    }
}

// ---------------------------------------------------------------------------
// Attention staging helpers (unchanged, HW-verified round 7).
// ---------------------------------------------------------------------------
__device__ __forceinline__ void stage_K(const float* __restrict__ src,
                                        __bf16* Khi, __bf16* Klo, int tid) {
    const int r0   = tid >> 4;
    const int c4   = (tid & 15) * 4;
    const int slot = (tid & 15) >> 1;
    const int half = (tid & 15) & 1;
#pragma unroll
    for (int i = 0; i < 4; ++i) {
        const int row = r0 + 16 * i;
        float4 v = *reinterpret_cast<const float4*>(&src[row * 64 + c4]);
        const int slotp = slot ^ (row & 7);
        const int idx = row * 64 + slotp * 8 + half * 4;
        bf16x4 hv, lv;
        __bf16 h0, l0;
        split2(v.x, h0, l0); hv[0] = h0; lv[0] = l0;
        split2(v.y, h0, l0); hv[1] = h0; lv[1] = l0;
        split2(v.z, h0, l0); hv[2] = h0; lv[2] = l0;
        split2(v.w, h0, l0); hv[3] = h0; lv[3] = l0;
        *reinterpret_cast<bf16x4*>(Khi + idx) = hv;
        *reinterpret_cast<bf16x4*>(Klo + idx) = lv;
    }
}

__device__ __forceinline__ void stage_V(const float* __restrict__ src,
                                        __bf16* Vhi, __bf16* Vlo, int tid) {
    const int kb  = tid >> 4;
    const int dq  = (tid & 15) * 4;
    const int kg  = kb >> 1;
    const int kc0 = (kb & 1) * 4;
    float rv[16];
#pragma unroll
    for (int i = 0; i < 4; ++i) {
        float4 t = *reinterpret_cast<const float4*>(&src[(kb * 4 + i) * 64 + dq]);
        rv[i * 4 + 0] = t.x; rv[i * 4 + 1] = t.y;
        rv[i * 4 + 2] = t.z; rv[i * 4 + 3] = t.w;
    }
#pragma unroll
    for (int di = 0; di < 4; ++di) {
        bf16x4 hv, lv;
        __bf16 h0, l0;
        split2(rv[0 * 4 + di], h0, l0); hv[0] = h0; lv[0] = l0;
        split2(rv[1 * 4 + di], h0, l0); hv[1] = h0; lv[1] = l0;
        split2(rv[2 * 4 + di], h0, l0); hv[2] = h0; lv[2] = l0;
        split2(rv[3 * 4 + di], h0, l0); hv[3] = h0; lv[3] = l0;
        const int idx = (kg * 64 + (dq + di)) * 8 + kc0;
        *reinterpret_cast<bf16x4*>(Vhi + idx) = hv;
        *reinterpret_cast<bf16x4*>(Vlo + idx) = lv;
    }
}

__device__ __forceinline__ void qk_tile(const __bf16* Khi, const __bf16* Klo,
                                        const bf16x8* qh, const bf16x8* ql,
                                        int lr, int lq, bool diag,
                                        int qrow0, int k0, f32x4 lg[4]) {
#pragma unroll
    for (int s = 0; s < 4; ++s) {
        f32x4 a = {0.f, 0.f, 0.f, 0.f};
        const int row = 16 * s + lr;
#pragma unroll
        for (int c = 0; c < 2; ++c) {
            const int slotp = (4 * c + lq) ^ (row & 7);
            bf16x8 kh = *reinterpret_cast<const bf16x8*>(Khi + row * 64 + slotp * 8);
            bf16x8 kl = *reinterpret_cast<const bf16x8*>(Klo + row * 64 + slotp * 8);
            a = mfma16(qh[c], kh, a);
            a = mfma16(ql[c], kh, a);
            a = mfma16(qh[c], kl, a);
        }
#pragma unroll
        for (int r = 0; r < 4; ++r) {
            float v = a[r] * 0.125f;
            if (diag && (k0 + 16 * s + lr) > (qrow0 + lq * 4 + r)) v = -1e30f;
            lg[s][r] = v;
        }
    }
}

// ---------------------------------------------------------------------------
// Kernel 2: causal attention. (unchanged, verified rounds 7/9)
// ---------------------------------------------------------------------------
__global__ __launch_bounds__(256, 3)
void attn_kernel(const float* __restrict__ Qg, const float* __restrict__ Kg,
                 const float* __restrict__ Vg, float* __restrict__ wts,
                 float* __restrict__ ctx) {
    __shared__ __align__(16) __bf16 Khi[4096];
    __shared__ __align__(16) __bf16 Klo[4096];
    __shared__ __align__(16) __bf16 Vhi[4096];
    __shared__ __align__(16) __bf16 Vlo[4096];
    __shared__ float sc[64][68];

    const int qt = blockIdx.x, h = blockIdx.y, b = blockIdx.z;
    const int q0 = qt * 64;
    const int tid = threadIdx.x;
    const int lane = tid & 63;
    const int w  = tid >> 6;
    const int lr = lane & 15;
    const int lq = lane >> 4;

    const size_t headbase = (size_t)(b * H_ + h) * S_ * D_;
    const float* Qp = Qg + headbase;
    const float* Kp = Kg + headbase;
    const float* Vp = Vg + headbase;
    float* wrow = wts + ((size_t)(b * H_ + h) * S_ + q0) * S_;

    bf16x8 qh[2], ql[2];
    {
        const int qrow = q0 + 16 * w + lr;
#pragma unroll
        for (int c = 0; c < 2; ++c) {
            const float* qp = &Qp[(size_t)qrow * D_ + c * 32 + lq * 8];
            float4 a  = *reinterpret_cast<const float4*>(qp);
            float4 bq = *reinterpret_cast<const float4*>(qp + 4);
            float v8[8] = {a.x, a.y, a.z, a.w, bq.x, bq.y, bq.z, bq.w};
#pragma unroll
            for (int j = 0; j < 8; ++j) {
                __bf16 h0, l0;
                split2(v8[j], h0, l0);
                qh[c][j] = h0; ql[c][j] = l0;
            }
        }
    }

    const int nkt = qt + 1;
    const int qrow0 = q0 + 16 * w;

    float m_run[4], l_run[4];
#pragma unroll
    for (int r = 0; r < 4; ++r) { m_run[r] = -INFINITY; l_run[r] = 0.f; }

    // ---------------- pass 1: row max + denom ----------------
    for (int kt = 0; kt < nkt; ++kt) {
        __syncthreads();
        stage_K(&Kp[(size_t)kt * 4096], Khi, Klo, tid);
        __syncthreads();
        f32x4 lg[4];
        qk_tile(Khi, Klo, qh, ql, lr, lq, kt == qt, qrow0, kt * 64, lg);
#pragma unroll
        for (int r = 0; r < 4; ++r) {
            float mx = fmaxf(fmaxf(lg[0][r], lg[1][r]), fmaxf(lg[2][r], lg[3][r]));
            mx = fmaxf(mx, __shfl_xor(mx, 1));
            mx = fmaxf(mx, __shfl_xor(mx, 2));
            mx = fmaxf(mx, __shfl_xor(mx, 4));
            mx = fmaxf(mx, __shfl_xor(mx, 8));
            const float mnew = fmaxf(m_run[r], mx);
            float ps = __expf(lg[0][r] - mnew) + __expf(lg[1][r] - mnew) +
                       __expf(lg[2][r] - mnew) + __expf(lg[3][r] - mnew);
            ps += __shfl_xor(ps, 1);
            ps += __shfl_xor(ps, 2);
            ps += __shfl_xor(ps, 4);
            ps += __shfl_xor(ps, 8);
            l_run[r] = l_run[r] * __expf(m_run[r] - mnew) + ps;
            m_run[r] = mnew;
        }
    }

    float linv[4];
#pragma unroll
    for (int r = 0; r < 4; ++r) linv[r] = 1.0f / l_run[r];

    // ---------------- pass 2: weights + PV ----------------
    f32x4 acc[4];
#pragma unroll
    for (int s = 0; s < 4; ++s) acc[s] = (f32x4){0.f, 0.f, 0.f, 0.f};

    for (int kt = 0; kt < nkt; ++kt) {
        __syncthreads();
        stage_K(&Kp[(size_t)kt * 4096], Khi, Klo, tid);
        stage_V(&Vp[(size_t)kt * 4096], Vhi, Vlo, tid);
        __syncthreads();

        f32x4 lg[4];
        qk_tile(Khi, Klo, qh, ql, lr, lq, kt == qt, qrow0, kt * 64, lg);
#pragma unroll
        for (int s = 0; s < 4; ++s)
#pragma unroll
            for (int r = 0; r < 4; ++r)
                sc[16 * w + lq * 4 + r][16 * s + lr] =
                    __expf(lg[s][r] - m_run[r]) * linv[r];
        __syncthreads();

        {
            const int c4 = (tid & 15) * 4;
            const int r0 = tid >> 4;
#pragma unroll
            for (int i = 0; i < 4; ++i) {
                const int row = r0 + 16 * i;
                float4 w4 = *reinterpret_cast<const float4*>(&sc[row][c4]);
                *reinterpret_cast<float4*>(
                    &wrow[(size_t)row * S_ + kt * 64 + c4]) = w4;
            }
        }

        bf16x8 pah[2], pal[2];
#pragma unroll
        for (int c = 0; c < 2; ++c) {
            const float* pr = &sc[16 * w + lr][lq * 8 + 32 * c];
            float4 p0 = *reinterpret_cast<const float4*>(pr);
            float4 p1 = *reinterpret_cast<const float4*>(pr + 4);
            float v8[8] = {p0.x, p0.y, p0.z, p0.w, p1.x, p1.y, p1.z, p1.w};
#pragma unroll
            for (int j = 0; j < 8; ++j) {
                __bf16 h0, l0;
                split2(v8[j], h0, l0);
                pah[c][j] = h0; pal[c][j] = l0;
            }
        }

#pragma unroll
        for (int s2 = 0; s2 < 4; ++s2) {
#pragma unroll
            for (int c = 0; c < 2; ++c) {
                const int kg = 4 * c + lq;
                const int d  = 16 * s2 + lr;
                bf16x8 vh = *reinterpret_cast<const bf16x8*>(Vhi + (kg * 64 + d) * 8);
                bf16x8 vl = *reinterpret_cast<const bf16x8*>(Vlo + (kg * 64 + d) * 8);
                acc[s2] = mfma16(pah[c], vh, acc[s2]);
                acc[s2] = mfma16(pah[c], vl, acc[s2]);
                acc[s2] = mfma16(pal[c], vh, acc[s2]);
            }
        }
    }

    {
        float4 z = {0.f, 0.f, 0.f, 0.f};
        const int c4 = (tid & 15) * 4;
        const int r0 = tid >> 4;
        for (int kt = nkt; kt < S_ / 64; ++kt) {
#pragma unroll
            for (int i = 0; i < 4; ++i) {
                const int row = r0 + 16 * i;
                *reinterpret_cast<float4*>(
                    &wrow[(size_t)row * S_ + kt * 64 + c4]) = z;
            }
        }
    }

#pragma unroll
    for (int s2 = 0; s2 < 4; ++s2)
#pragma unroll
        for (int r = 0; r < 4; ++r)
            ctx[((size_t)b * S_ + qrow0 + lq * 4 + r) * E_ + h * 64 + 16 * s2 + lr] =
                acc[s2][r];
}

// ---------------------------------------------------------------------------
// Kernel 3: out = ctx @ w_out + b_out, from packs. Grid (E/128, M/128).
// ---------------------------------------------------------------------------
__global__ __launch_bounds__(256, 2)
void proj_kernel(const ushort* __restrict__ ch, const ushort* __restrict__ cl,
                 const ushort* __restrict__ wh, const ushort* __restrict__ wl,
                 const float* __restrict__ bias, float* __restrict__ out) {
    __shared__ __align__(16) __bf16 lAh[4096], lAl[4096];
    __shared__ __align__(16) __bf16 lBh[4096], lBl[4096];
    constexpr int KT = E_ / 32;

    const int pn = blockIdx.x;
    const int pm = blockIdx.y;
    const int bn = pn * 128, bm = pm * 128;
    const int tid  = threadIdx.x;
    const int lane = tid & 63;
    const int w    = tid >> 6;
    const int lr   = lane & 15;
    const int lq   = lane >> 4;
    const int wm   = w >> 1, wn = w & 1;

    f32x4 acc[4][4];
#pragma unroll
    for (int mi = 0; mi < 4; ++mi)
#pragma unroll
        for (int ni = 0; ni < 4; ++ni) acc[mi][ni] = (f32x4){0.f, 0.f, 0.f, 0.f};

    gemm_packed_core(ch + (size_t)pm * KT * 4096, cl + (size_t)pm * KT * 4096,
                     wh + (size_t)pn * KT * 4096, wl + (size_t)pn * KT * 4096,
                     KT, lAh, lAl, lBh, lBl, acc);

#pragma unroll
    for (int ni = 0; ni < 4; ++ni) {
        const int col = bn + (wn * 4 + ni) * 16 + lr;
        const float bv = bias[col];
#pragma unroll
        for (int mi = 0; mi < 4; ++mi) {
#pragma unroll
            for (int r = 0; r < 4; ++r) {
                const int row = bm + (wm * 4 + mi) * 16 + lq * 4 + r;
                out[(size_t)row * E_ + col] = acc[mi][ni][r] + bv;
            }
        }
    }
}

// ---------------------------------------------------------------------------
extern "C" void kernel_launch(void* const* d_in, const int* in_sizes, int n_in,
                              void* d_out, int out_size, void* d_ws,
                              size_t ws_size, hipStream_t stream) {
    (void)in_sizes; (void)n_in; (void)out_size; (void)ws_size;
    const float* x     = (const float*)d_in[0];
    const float* w_qkv = (const float*)d_in[1];
    const float* b_qkv = (const float*)d_in[2];
    const float* w_out = (const float*)d_in[3];
    const float* b_out = (const float*)d_in[4];

    float* out = (float*)d_out;                       // [B,S,E]
    float* wts = out + (size_t)M_ * E_;               // [B,H,S,S]

    const size_t per = (size_t)B_ * H_ * S_ * D_;     // 8,388,608 floats
    float* Qb  = (float*)d_ws;
    float* Kb  = Qb + per;
    float* Vb  = Kb + per;
    float* ctx = Vb + per;                            // [B,S,E] merged heads

    // bf16 pack region after the fp32 buffers (ws is multi-GB; ~185 MB used)
    ushort* xh  = (ushort*)(ctx + per);               // 8,388,608 each
    ushort* xl  = xh  + per;
    ushort* wqh = xl  + per;                          // 3,145,728 each
    ushort* wql = wqh + (size_t)E_ * N3;
    ushort* woh = wql + (size_t)E_ * N3;              // 1,048,576 each
    ushort* wol = woh + (size_t)E_ * E_;
    // ctx pack reuses the Qb region (dead after attn): 2 x 8.39M ushort fits
    ushort* ch  = (ushort*)Qb;
    ushort* cl  = ch + per;

    // ---- packs ----
    pack_A_kernel<<<(M_ / 128) * (E_ / 32) * 2, 256, 0, stream>>>(x, E_, xh, xl);
    pack_B_kernel<<<(N3 / 128) * (E_ / 32) * 2, 256, 0, stream>>>(
        w_qkv, E_, N3, wqh, wql);
    pack_B_kernel<<<(E_ / 128) * (E_ / 32) * 2, 256, 0, stream>>>(
        w_out, E_, E_, woh, wol);

    // ---- main pipeline ----
    qkv_kernel<<<dim3(N3 / 128, M_ / 128), 256, 0, stream>>>(
        xh, xl, wqh, wql, b_qkv, Qb, Kb, Vb);
    attn_kernel<<<dim3(S_ / 64, H_, B_), 256, 0, stream>>>(
        Qb, Kb, Vb, wts, ctx);
    pack_A_kernel<<<(M_ / 128) * (E_ / 32) * 2, 256, 0, stream>>>(ctx, E_, ch, cl);
    proj_kernel<<<dim3(E_ / 128, M_ / 128), 256, 0, stream>>>(
        ch, cl, woh, wol, b_out, out);
}